// Round 14
// baseline (190.164 us; speedup 1.0000x reference)
//
#include <hip/hip_runtime.h>
#include <math.h>

#define D 128
#define SCAN_CHUNK 256
#define BKT_SHIFT 7              // 128 dst per bucket
#define CELL_CAP 512             // per (bucket, sub) capacity

typedef __attribute__((ext_vector_type(8))) short short8;
typedef __attribute__((ext_vector_type(4))) float f32x4;

__device__ __forceinline__ unsigned short f2bf(float f) {
    unsigned u = __float_as_uint(f);
    unsigned r = (u + 0x7fff + ((u >> 16) & 1)) >> 16;   // RNE
    return (unsigned short)r;
}
__device__ __forceinline__ float bflo(unsigned u) { return __uint_as_float(u << 16); }
__device__ __forceinline__ float bfhi(unsigned u) { return __uint_as_float(u & 0xffff0000u); }

// ---------------- init: pack Wl|Wr (blocks 0-15) + zero deg/deghist/bcur ----------------
__global__ __launch_bounds__(256) void init_pack_k(const float* __restrict__ Wl,
    const float* __restrict__ Wr, unsigned short* __restrict__ wpack,
    int* __restrict__ deg, int* __restrict__ deghist, int* __restrict__ bcur,
    int n, int ncell, int nzb)
{
    if (blockIdx.x < 16) {
        const int lane = threadIdx.x & 63;
        const int wv = threadIdx.x >> 6;
        const int slot = blockIdx.x * 4 + wv;     // slots 0..63
        const int ct = slot >> 2;
        const int kt = slot & 3;
        const float* W = (ct < 8) ? Wl : Wr;
        const int cb = (ct & 7) * 16 + (lane & 15);
        const int kb = kt * 32 + (lane >> 4) * 8;
        unsigned short v[8];
#pragma unroll
        for (int i = 0; i < 8; i++) v[i] = f2bf(W[(size_t)(kb + i) * D + cb]);
        *(uint4*)(wpack + ((size_t)slot << 9) + lane * 8) = *(uint4*)v;
    } else {
        const int tid = (blockIdx.x - 16) * 256 + threadIdx.x;
        const int stride = nzb * 256;
        for (int i = tid; i < n; i += stride) deg[i] = 0;
        for (int i = tid; i < ncell; i += stride) bcur[i] = 0;
        if (tid < 256) deghist[tid] = 0;
    }
}

// ---------------- fused mid: gemm (blocks [0,G1)) | hist | coarse-append pass1 ----------------
__global__ __launch_bounds__(256) void fused_mid_k(const float* __restrict__ x,
    const unsigned short* __restrict__ wpack, const float* __restrict__ bl,
    const float* __restrict__ br, unsigned* __restrict__ xlb, float* __restrict__ xr,
    const int* __restrict__ ei, const float* __restrict__ ea,
    int* __restrict__ deg, int* __restrict__ bcur, uint2* __restrict__ coarse,
    int n, int E, int G1, int G2)
{
    const int b = blockIdx.x;
    if (b < G1) {
        // ---- MFMA GEMM: xl(bf16 packed) = x@Wl+bl, xr(f32) = x@Wr+br ----
        const int lane = threadIdx.x & 63;
        const int wv = threadIdx.x >> 6;
        const int rt = b * 4 + wv;
        if (rt * 16 >= n) return;
        const int r0 = rt * 16;
        const int ra = r0 + (lane & 15);
        const int r = ra < n ? ra : n - 1;
        const int ko = (lane >> 4) * 8;

        short8 a[4];
#pragma unroll
        for (int kt = 0; kt < 4; kt++) {
            const float* px = x + (size_t)r * D + kt * 32 + ko;
            float4 lo = *(const float4*)px;
            float4 hi = *(const float4*)(px + 4);
            short8 t;
            t[0] = (short)f2bf(lo.x); t[1] = (short)f2bf(lo.y);
            t[2] = (short)f2bf(lo.z); t[3] = (short)f2bf(lo.w);
            t[4] = (short)f2bf(hi.x); t[5] = (short)f2bf(hi.y);
            t[6] = (short)f2bf(hi.z); t[7] = (short)f2bf(hi.w);
            a[kt] = t;
        }

        f32x4 acc[16];
#pragma unroll
        for (int i = 0; i < 16; i++) acc[i] = (f32x4){0.f, 0.f, 0.f, 0.f};

#pragma unroll
        for (int kt = 0; kt < 4; kt++) {
#pragma unroll
            for (int ct = 0; ct < 16; ct++) {
                short8 bb = *(const short8*)(wpack + (((size_t)(ct * 4 + kt)) << 9) + lane * 8);
                acc[ct] = __builtin_amdgcn_mfma_f32_16x16x32_bf16(a[kt], bb, acc[ct], 0, 0, 0);
            }
        }

        const int colb = lane & 15;
        const int rbase = r0 + (lane >> 4) * 4;
#pragma unroll
        for (int ct = 8; ct < 16; ct++) {
            const int c = (ct - 8) * 16 + colb;
            const float bb = br[c];
#pragma unroll
            for (int reg = 0; reg < 4; reg++) {
                const int row = rbase + reg;
                if (row < n) xr[(size_t)row * D + c] = acc[ct][reg] + bb;
            }
        }
#pragma unroll
        for (int ct = 0; ct < 8; ct++) {
            const int c = ct * 16 + colb;
            const float bb = bl[c];
#pragma unroll
            for (int reg = 0; reg < 4; reg++) {
                unsigned mybf = f2bf(acc[ct][reg] + bb);
                unsigned other = (unsigned)__shfl_xor((int)mybf, 1);
                if ((lane & 1) == 0) {
                    const int row = rbase + reg;
                    if (row < n) xlb[(size_t)row * 64 + (c >> 1)] = mybf | (other << 16);
                }
            }
        }
    } else if (b < G1 + G2) {
        // ---- degree histogram ----
        const int e = (b - G1) * 256 + threadIdx.x;
        if (e < E) atomicAdd(&deg[ei[E + e]], 1);
    } else {
        // ---- pass1: append {src|ea, dst} to (bucket, xcd-proxy) cell ----
        const int e = (b - G1 - G2) * 256 + threadIdx.x;
        if (e < E) {
            const int dst = ei[E + e];
            const int src = ei[e];
            const int cell = ((dst >> BKT_SHIFT) << 3) | (b & 7);
            const int pos = atomicAdd(&bcur[cell], 1);
            if (pos < CELL_CAP)
                coarse[((size_t)cell << 9) + pos] =
                    make_uint2(((unsigned)src << 16) | (unsigned)f2bf(ea[e]), (unsigned)dst);
        }
    }
}

// ---------------- scan stage 1: per-block chunk sums + degree histogram ----------------
__global__ __launch_bounds__(256) void scan_sum_k(const int* __restrict__ deg,
    int* __restrict__ bsum, int* __restrict__ deghist, int n)
{
    __shared__ int lh[256];
    const int t = threadIdx.x;
    lh[t] = 0;
    __syncthreads();
    const int i = blockIdx.x * SCAN_CHUNK + t;
    int s = 0;
    if (i < n) {
        s = deg[i];
        atomicAdd(&lh[min(s, 255)], 1);
    }
#pragma unroll
    for (int off = 32; off > 0; off >>= 1) s += __shfl_xor(s, off);
    __shared__ int ws_[4];
    const int lane = t & 63, w = t >> 6;
    if (lane == 0) ws_[w] = s;
    __syncthreads();
    if (t == 0) bsum[blockIdx.x] = ws_[0] + ws_[1] + ws_[2] + ws_[3];
    if (lh[t]) atomicAdd(&deghist[t], lh[t]);
}

// ---------------- scan stage 2: exclusive scans (block sums + degree bins) ----------------
__global__ __launch_bounds__(256) void scan_off_k(const int* __restrict__ bsum,
    int* __restrict__ boff, int* __restrict__ rowptr,
    const int* __restrict__ deghist, int* __restrict__ degcur, int nb, int n)
{
    const int t = threadIdx.x;
    const int lane = t & 63, w = t >> 6;
    int v = (t < nb) ? bsum[t] : 0;
    int inc = v;
#pragma unroll
    for (int off = 1; off < 64; off <<= 1) {
        int u = __shfl_up(inc, off);
        if (lane >= off) inc += u;
    }
    __shared__ int wsum[4], wpre[4];
    if (lane == 63) wsum[w] = inc;
    __syncthreads();
    if (t == 0) {
        int r = 0;
#pragma unroll
        for (int j = 0; j < 4; j++) { wpre[j] = r; r += wsum[j]; }
        rowptr[n] = r;
    }
    __syncthreads();
    if (t < nb) boff[t] = inc - v + wpre[w];
    int dv = deghist[t];
    int dinc = dv;
#pragma unroll
    for (int off = 1; off < 64; off <<= 1) {
        int u = __shfl_up(dinc, off);
        if (lane >= off) dinc += u;
    }
    __shared__ int w2sum[4], w2pre[4];
    if (lane == 63) w2sum[w] = dinc;
    __syncthreads();
    if (t == 0) {
        int r = 0;
#pragma unroll
        for (int j = 0; j < 4; j++) { w2pre[j] = r; r += w2sum[j]; }
    }
    __syncthreads();
    degcur[t] = dinc - dv + w2pre[w];
}

// ---------------- scan stage 3: rowptr + degree-sorted node order ----------------
__global__ __launch_bounds__(256) void scan_fin_k(int* __restrict__ deg,
    const int* __restrict__ boff, int* __restrict__ rowptr,
    int* __restrict__ degcur, int* __restrict__ nodeord, int n)
{
    __shared__ int wsum[4], wpre[4];
    __shared__ int lh[256], lbase[256];
    const int t = threadIdx.x;
    const int i = blockIdx.x * SCAN_CHUNK + t;
    lh[t] = 0;
    int v = (i < n) ? deg[i] : 0;
    const int bin = min(v, 255);
    const int lane = t & 63, w = t >> 6;
    int inc = v;
#pragma unroll
    for (int off = 1; off < 64; off <<= 1) {
        int u = __shfl_up(inc, off);
        if (lane >= off) inc += u;
    }
    if (lane == 63) wsum[w] = inc;
    __syncthreads();
    if (t == 0) {
        int r = 0;
#pragma unroll
        for (int j = 0; j < 4; j++) { wpre[j] = r; r += wsum[j]; }
    }
    __syncthreads();
    int rank = 0;
    if (i < n) {
        rank = atomicAdd(&lh[bin], 1);
        int ex = inc - v + wpre[w] + boff[blockIdx.x];
        rowptr[i] = ex;
        deg[i] = ex;
    }
    __syncthreads();
    lbase[t] = lh[t] ? atomicAdd(&degcur[t], lh[t]) : 0;
    __syncthreads();
    if (i < n) nodeord[lbase[bin] + rank] = i;
}

// ---------------- pass2: drain cells -> final CSR slots (LDS cursors) ----------------
__global__ __launch_bounds__(256) void pass2_k(const uint2* __restrict__ coarse,
    const int* __restrict__ bcur, const int* __restrict__ rowptr,
    unsigned* __restrict__ edges, int n)
{
    __shared__ int lcur[1 << BKT_SHIFT];
    const int b = blockIdx.x;
    const int t = threadIdx.x;
    const int d0 = b << BKT_SHIFT;
    if (t < (1 << BKT_SHIFT) && d0 + t < n) lcur[t] = rowptr[d0 + t];
    __syncthreads();
#pragma unroll
    for (int sub = 0; sub < 8; sub++) {
        const int cell = (b << 3) | sub;
        const int cnt = min(bcur[cell], CELL_CAP);
        const uint2* base = coarse + ((size_t)cell << 9);
        for (int i = t; i < cnt; i += 256) {
            const uint2 en = base[i];
            const int ld = (int)en.y - d0;
            const int pos = atomicAdd(&lcur[ld], 1);
            edges[pos] = en.x;
        }
    }
}

// ---------------- fused: edge logits + online softmax + aggregate
//                   + residual + GELU(erf) + BN-stats ----------------
__global__ __launch_bounds__(256) void agg_k(const unsigned* __restrict__ xlb,
    const float* __restrict__ xr, const float* __restrict__ x,
    const float* __restrict__ bias, const int* __restrict__ rowptr,
    const unsigned* __restrict__ edges, const float* __restrict__ We,
    const float* __restrict__ att, const int* __restrict__ nodeord,
    unsigned* __restrict__ hbf, float* __restrict__ partials, int n)
{
    const int t = threadIdx.x;
    const int gg = (blockIdx.x * 256 + t) >> 4;
    const int li = t & 15;
    const int f0 = li * 8;
    const bool active = gg < n;

    float sum[8], sq[8];
#pragma unroll
    for (int k = 0; k < 8; k++) { sum[k] = 0.f; sq[k] = 0.f; }

    if (active) {
        const int v = nodeord[n - 1 - gg];   // descending degree
        const int beg = rowptr[v];
        const int end = rowptr[v + 1];

        float xrv[8], wev[8], atv[8];
        {
            float4 a0 = *(const float4*)(xr + (size_t)v * D + f0);
            float4 a1 = *(const float4*)(xr + (size_t)v * D + f0 + 4);
            xrv[0]=a0.x; xrv[1]=a0.y; xrv[2]=a0.z; xrv[3]=a0.w;
            xrv[4]=a1.x; xrv[5]=a1.y; xrv[6]=a1.z; xrv[7]=a1.w;
            float4 w0 = *(const float4*)(We + f0);
            float4 w1 = *(const float4*)(We + f0 + 4);
            wev[0]=w0.x; wev[1]=w0.y; wev[2]=w0.z; wev[3]=w0.w;
            wev[4]=w1.x; wev[5]=w1.y; wev[6]=w1.z; wev[7]=w1.w;
            float4 t0 = *(const float4*)(att + f0);
            float4 t1 = *(const float4*)(att + f0 + 4);
            atv[0]=t0.x; atv[1]=t0.y; atv[2]=t0.z; atv[3]=t0.w;
            atv[4]=t1.x; atv[5]=t1.y; atv[6]=t1.z; atv[7]=t1.w;
        }

        float m = -1e30f, s = 0.f;
        float acc[8];
#pragma unroll
        for (int k = 0; k < 8; k++) acc[k] = 0.f;

        int j = beg;
        unsigned pk0 = 0u, pk1 = 0u;
        uint4 xb0 = make_uint4(0,0,0,0), xb1 = make_uint4(0,0,0,0);
        if (j < end) {
            pk0 = edges[j];
            const int j1 = (j + 1 < end) ? j + 1 : end - 1;
            pk1 = edges[j1];
            xb0 = *(const uint4*)(xlb + (size_t)(pk0 >> 16) * 64 + li * 4);
            xb1 = *(const uint4*)(xlb + (size_t)(pk1 >> 16) * 64 + li * 4);
        }
        while (j < end) {
            const int jn = j + 2;
            unsigned pn0 = pk0, pn1 = pk1;
            uint4 xn0 = xb0, xn1 = xb1;
            if (jn < end) {
                pn0 = edges[jn];
                const int j3 = (jn + 1 < end) ? jn + 1 : end - 1;
                pn1 = edges[j3];
                xn0 = *(const uint4*)(xlb + (size_t)(pn0 >> 16) * 64 + li * 4);
                xn1 = *(const uint4*)(xlb + (size_t)(pn1 >> 16) * 64 + li * 4);
            }

            const float ea0 = bflo(pk0);
            const float ea1 = bflo(pk1);
            float xv0[8], xv1[8];
            xv0[0] = bflo(xb0.x); xv0[1] = bfhi(xb0.x);
            xv0[2] = bflo(xb0.y); xv0[3] = bfhi(xb0.y);
            xv0[4] = bflo(xb0.z); xv0[5] = bfhi(xb0.z);
            xv0[6] = bflo(xb0.w); xv0[7] = bfhi(xb0.w);
            xv1[0] = bflo(xb1.x); xv1[1] = bfhi(xb1.x);
            xv1[2] = bflo(xb1.y); xv1[3] = bfhi(xb1.y);
            xv1[4] = bflo(xb1.z); xv1[5] = bfhi(xb1.z);
            xv1[6] = bflo(xb1.w); xv1[7] = bfhi(xb1.w);

            float p0 = 0.f, p1 = 0.f;
#pragma unroll
            for (int k = 0; k < 8; k++) {
                float t0 = fmaf(ea0, wev[k], xrv[k]) + xv0[k];
                t0 = fmaxf(t0, 0.2f * t0);
                p0 = fmaf(t0, atv[k], p0);
                float t1 = fmaf(ea1, wev[k], xrv[k]) + xv1[k];
                t1 = fmaxf(t1, 0.2f * t1);
                p1 = fmaf(t1, atv[k], p1);
            }
#pragma unroll
            for (int off = 8; off >= 1; off >>= 1) {
                p0 += __shfl_xor(p0, off);
                p1 += __shfl_xor(p1, off);
            }
            if (j + 1 >= end) p1 = -1e30f;    // mask odd tail

            const float pm = fmaxf(m, fmaxf(p0, p1));
            const float sc = __expf(m - pm);
            const float w0 = __expf(p0 - pm);
            const float w1 = __expf(p1 - pm);
            s = s * sc + w0 + w1;
#pragma unroll
            for (int k = 0; k < 8; k++)
                acc[k] = fmaf(acc[k], sc, fmaf(w0, xv0[k], w1 * xv1[k]));
            m = pm;

            pk0 = pn0; pk1 = pn1; xb0 = xn0; xb1 = xn1; j = jn;
        }

        const float inv = 1.f / (s + 1e-16f);
        float xa[8], bb[8];
        {
            float4 a0 = *(const float4*)(x + (size_t)v * D + f0);
            float4 a1 = *(const float4*)(x + (size_t)v * D + f0 + 4);
            xa[0]=a0.x; xa[1]=a0.y; xa[2]=a0.z; xa[3]=a0.w;
            xa[4]=a1.x; xa[5]=a1.y; xa[6]=a1.z; xa[7]=a1.w;
            float4 b0 = *(const float4*)(bias + f0);
            float4 b1 = *(const float4*)(bias + f0 + 4);
            bb[0]=b0.x; bb[1]=b0.y; bb[2]=b0.z; bb[3]=b0.w;
            bb[4]=b1.x; bb[5]=b1.y; bb[6]=b1.z; bb[7]=b1.w;
        }
        float ge[8];
#pragma unroll
        for (int k = 0; k < 8; k++) {
            const float hv = xa[k] + fmaf(acc[k], inv, bb[k]);
            const float g = 0.5f * hv * (1.f + erff(hv * 0.70710678118654752f));
            ge[k] = g;
            sum[k] = g;
            sq[k] = g * g;
        }
        unsigned o0 = (unsigned)f2bf(ge[0]) | ((unsigned)f2bf(ge[1]) << 16);
        unsigned o1 = (unsigned)f2bf(ge[2]) | ((unsigned)f2bf(ge[3]) << 16);
        unsigned o2 = (unsigned)f2bf(ge[4]) | ((unsigned)f2bf(ge[5]) << 16);
        unsigned o3 = (unsigned)f2bf(ge[6]) | ((unsigned)f2bf(ge[7]) << 16);
        *(uint4*)(hbf + (size_t)v * 64 + li * 4) = make_uint4(o0, o1, o2, o3);
    }

    // merge 4 groups via shuffles; coalesced partials write
#pragma unroll
    for (int k = 0; k < 8; k++) {
        sum[k] += __shfl_xor(sum[k], 16);
        sum[k] += __shfl_xor(sum[k], 32);
        sq[k]  += __shfl_xor(sq[k], 16);
        sq[k]  += __shfl_xor(sq[k], 32);
    }
    __shared__ float redS[4][128], redQ[4][128];
    const int wv_ = t >> 6;
    const int lane_ = t & 63;
    if (lane_ < 16) {
#pragma unroll
        for (int k = 0; k < 8; k++) {
            redS[wv_][f0 + k] = sum[k];
            redQ[wv_][f0 + k] = sq[k];
        }
    }
    __syncthreads();
    if (t < 128) {
        const float ts = redS[0][t] + redS[1][t] + redS[2][t] + redS[3][t];
        const float tq = redQ[0][t] + redQ[1][t] + redQ[2][t] + redQ[3][t];
        partials[(size_t)blockIdx.x * 256 + t] = ts;
        partials[(size_t)blockIdx.x * 256 + 128 + t] = tq;
    }
}

// ---------------- reduce partials + fold BN params ----------------
__global__ __launch_bounds__(256) void bn_reduce_params_k(const float* __restrict__ partials,
    const float* __restrict__ gamma, const float* __restrict__ beta,
    float* __restrict__ ab, float n, int nblk)
{
    const int c = blockIdx.x;
    const int t = threadIdx.x;
    float s = 0.f, q = 0.f;
    for (int b = t; b < nblk; b += 256) {
        s += partials[(size_t)b * 256 + c];
        q += partials[(size_t)b * 256 + 128 + c];
    }
#pragma unroll
    for (int off = 32; off > 0; off >>= 1) {
        s += __shfl_xor(s, off);
        q += __shfl_xor(q, off);
    }
    __shared__ float ss[4], qq[4];
    const int lane = t & 63, w = t >> 6;
    if (lane == 0) { ss[w] = s; qq[w] = q; }
    __syncthreads();
    if (t == 0) {
        float S = ss[0] + ss[1] + ss[2] + ss[3];
        float Q = qq[0] + qq[1] + qq[2] + qq[3];
        float mean = S / n;
        float var = Q / n - mean * mean;
        float a = rsqrtf(var + 1e-5f) * gamma[c];
        ab[c] = a;
        ab[c + 128] = beta[c] - mean * a;
    }
}

// ---------------- BN apply (bf16 h -> f32 out) ----------------
__global__ __launch_bounds__(256) void bn_apply_k(const unsigned* __restrict__ hbf,
    float* __restrict__ out, const float* __restrict__ ab, int total4)
{
    int i4 = blockIdx.x * blockDim.x + threadIdx.x;
    if (i4 >= total4) return;
    int cg = i4 & 31;
    uint2 hp = *(const uint2*)(hbf + (size_t)i4 * 2);
    float4 a = ((const float4*)ab)[cg];
    float4 b = ((const float4*)(ab + 128))[cg];
    ((float4*)out)[i4] = make_float4(bflo(hp.x) * a.x + b.x, bfhi(hp.x) * a.y + b.y,
                                     bflo(hp.y) * a.z + b.z, bfhi(hp.y) * a.w + b.w);
}

extern "C" void kernel_launch(void* const* d_in, const int* in_sizes, int n_in,
                              void* d_out, int out_size, void* d_ws, size_t ws_size,
                              hipStream_t stream)
{
    const float* x    = (const float*)d_in[0];
    const int*   ei   = (const int*)d_in[1];
    const float* ea   = (const float*)d_in[2];
    const float* Wl   = (const float*)d_in[3];
    const float* bl   = (const float*)d_in[4];
    const float* Wr   = (const float*)d_in[5];
    const float* br   = (const float*)d_in[6];
    const float* We   = (const float*)d_in[7];
    const float* att  = (const float*)d_in[8];
    const float* bias = (const float*)d_in[9];
    const float* gamma= (const float*)d_in[10];
    const float* beta = (const float*)d_in[11];
    float* out = (float*)d_out;

    const int n = in_sizes[0] / D;
    const int E = in_sizes[1] / 2;
    const int nb = (n + SCAN_CHUNK - 1) / SCAN_CHUNK;          // 196
    const int ablk = (n * 16 + 255) / 256;                     // 3125
    const int nbk = (n + (1 << BKT_SHIFT) - 1) >> BKT_SHIFT;   // 391
    const int ncell = nbk * 8;

    char* ws = (char*)d_ws;
    unsigned short* wpack = (unsigned short*)ws;        // 64 KB
    unsigned* xlb = (unsigned*)(ws + 65536);            // n*64 u32 (bf16 xl)
    // union: coarse (pass1/pass2) then hbf (agg onward) — pass2 finishes before agg writes
    char* ubase = (char*)(xlb + (size_t)n * 64);
    size_t usz = (size_t)ncell * CELL_CAP * 8;          // coarse bytes
    size_t hsz = (size_t)n * 64 * 4;                    // hbf bytes
    if (hsz > usz) usz = hsz;
    uint2* coarse = (uint2*)ubase;
    unsigned* hbf = (unsigned*)ubase;
    float* xr = (float*)(ubase + usz);                  // n*D f32
    int* deg = (int*)(xr + (size_t)n * D);              // n (becomes cursor)
    int* rowptr = deg + n;                              // n+1
    int* deghist = rowptr + n + 1;                      // 256
    int* degcur = deghist + 256;                        // 256
    int* nodeord = degcur + 256;                        // n
    int* bsum = nodeord + n;                            // nb
    int* boff = bsum + nb;                              // nb
    int* bcur = boff + nb;                              // ncell
    unsigned* edges = (unsigned*)(bcur + ncell);        // E u32 (packed src|ea)
    float* partials = (float*)(edges + E);              // 256*ablk
    float* ab = partials + (size_t)256 * ablk;          // 256

    const int nzb = 98;
    init_pack_k<<<16 + nzb, 256, 0, stream>>>(Wl, Wr, wpack, deg, deghist, bcur, n, ncell, nzb);

    const int nrt = (n + 15) / 16;
    const int G1 = (nrt + 3) / 4;                       // gemm blocks (782)
    const int G2 = (E + 255) / 256;                     // hist blocks (2500)
    const int G3 = (E + 255) / 256;                     // pass1 blocks (2500)
    fused_mid_k<<<G1 + G2 + G3, 256, 0, stream>>>(x, wpack, bl, br, xlb, xr,
                                                  ei, ea, deg, bcur, coarse, n, E, G1, G2);
    scan_sum_k<<<nb, 256, 0, stream>>>(deg, bsum, deghist, n);
    scan_off_k<<<1, 256, 0, stream>>>(bsum, boff, rowptr, deghist, degcur, nb, n);
    scan_fin_k<<<nb, 256, 0, stream>>>(deg, boff, rowptr, degcur, nodeord, n);
    pass2_k<<<nbk, 256, 0, stream>>>(coarse, bcur, rowptr, edges, n);
    agg_k<<<ablk, 256, 0, stream>>>(xlb, xr, x, bias, rowptr, edges, We, att,
                                    nodeord, hbf, partials, n);
    bn_reduce_params_k<<<128, 256, 0, stream>>>(partials, gamma, beta, ab, (float)n, ablk);
    const int total4 = (n * D) / 4;
    bn_apply_k<<<(total4 + 255) / 256, 256, 0, stream>>>(hbf, out, ab, total4);
}

// Round 15
// 169.709 us; speedup vs baseline: 1.1205x; 1.1205x over previous
//
#include <hip/hip_runtime.h>
#include <math.h>

#define D 128
#define SCAN_CHUNK 256

typedef __attribute__((ext_vector_type(8))) short short8;
typedef __attribute__((ext_vector_type(4))) float f32x4;

__device__ __forceinline__ unsigned short f2bf(float f) {
    unsigned u = __float_as_uint(f);
    unsigned r = (u + 0x7fff + ((u >> 16) & 1)) >> 16;   // RNE
    return (unsigned short)r;
}
__device__ __forceinline__ float bflo(unsigned u) { return __uint_as_float(u << 16); }
__device__ __forceinline__ float bfhi(unsigned u) { return __uint_as_float(u & 0xffff0000u); }

// ---------------- fused: pack Wl|Wr (blocks 0-15) + zero deg/deghist (rest) ----------------
__global__ __launch_bounds__(256) void init_pack_k(const float* __restrict__ Wl,
    const float* __restrict__ Wr, unsigned short* __restrict__ wpack,
    int* __restrict__ deg, int* __restrict__ deghist, int n, int nzb)
{
    if (blockIdx.x < 16) {
        const int lane = threadIdx.x & 63;
        const int wv = threadIdx.x >> 6;
        const int slot = blockIdx.x * 4 + wv;     // slots 0..63
        const int ct = slot >> 2;
        const int kt = slot & 3;
        const float* W = (ct < 8) ? Wl : Wr;
        const int cb = (ct & 7) * 16 + (lane & 15);
        const int kb = kt * 32 + (lane >> 4) * 8;
        unsigned short v[8];
#pragma unroll
        for (int i = 0; i < 8; i++) v[i] = f2bf(W[(size_t)(kb + i) * D + cb]);
        *(uint4*)(wpack + ((size_t)slot << 9) + lane * 8) = *(uint4*)v;
    } else {
        const int tid = (blockIdx.x - 16) * 256 + threadIdx.x;
        const int stride = nzb * 256;
        for (int i = tid; i < n; i += stride) deg[i] = 0;
        if (tid < 256) deghist[tid] = 0;
    }
}

// ---------------- MFMA GEMM: xl(bf16 packed) = x@Wl+bl, xr(f32) = x@Wr+br ----------------
__global__ __launch_bounds__(256) void gemm_mfma_k(const float* __restrict__ x,
    const unsigned short* __restrict__ wpack, const float* __restrict__ bl,
    const float* __restrict__ br, unsigned* __restrict__ xlb,
    float* __restrict__ xr, int n)
{
    const int lane = threadIdx.x & 63;
    const int wv = threadIdx.x >> 6;
    const int rt = blockIdx.x * 4 + wv;          // 16-row tile index
    if (rt * 16 >= n) return;
    const int r0 = rt * 16;
    const int ra = r0 + (lane & 15);
    const int r = ra < n ? ra : n - 1;
    const int ko = (lane >> 4) * 8;

    short8 a[4];
#pragma unroll
    for (int kt = 0; kt < 4; kt++) {
        const float* px = x + (size_t)r * D + kt * 32 + ko;
        float4 lo = *(const float4*)px;
        float4 hi = *(const float4*)(px + 4);
        short8 t;
        t[0] = (short)f2bf(lo.x); t[1] = (short)f2bf(lo.y);
        t[2] = (short)f2bf(lo.z); t[3] = (short)f2bf(lo.w);
        t[4] = (short)f2bf(hi.x); t[5] = (short)f2bf(hi.y);
        t[6] = (short)f2bf(hi.z); t[7] = (short)f2bf(hi.w);
        a[kt] = t;
    }

    f32x4 acc[16];
#pragma unroll
    for (int i = 0; i < 16; i++) acc[i] = (f32x4){0.f, 0.f, 0.f, 0.f};

#pragma unroll
    for (int kt = 0; kt < 4; kt++) {
#pragma unroll
        for (int ct = 0; ct < 16; ct++) {
            short8 b = *(const short8*)(wpack + (((size_t)(ct * 4 + kt)) << 9) + lane * 8);
            acc[ct] = __builtin_amdgcn_mfma_f32_16x16x32_bf16(a[kt], b, acc[ct], 0, 0, 0);
        }
    }

    const int colb = lane & 15;
    const int rbase = r0 + (lane >> 4) * 4;
#pragma unroll
    for (int ct = 8; ct < 16; ct++) {
        const int c = (ct - 8) * 16 + colb;
        const float bb = br[c];
#pragma unroll
        for (int reg = 0; reg < 4; reg++) {
            const int row = rbase + reg;
            if (row < n) xr[(size_t)row * D + c] = acc[ct][reg] + bb;
        }
    }
#pragma unroll
    for (int ct = 0; ct < 8; ct++) {
        const int c = ct * 16 + colb;
        const float bb = bl[c];
#pragma unroll
        for (int reg = 0; reg < 4; reg++) {
            unsigned mybf = f2bf(acc[ct][reg] + bb);
            unsigned other = (unsigned)__shfl_xor((int)mybf, 1);
            if ((lane & 1) == 0) {
                const int row = rbase + reg;
                if (row < n) xlb[(size_t)row * 64 + (c >> 1)] = mybf | (other << 16);
            }
        }
    }
}

// ---------------- CSR build: histogram (1 edge/thread, full grid) ----------------
__global__ __launch_bounds__(256) void hist_k(const int* __restrict__ ei,
    int* __restrict__ deg, int E)
{
    int e = blockIdx.x * blockDim.x + threadIdx.x;
    if (e < E) atomicAdd(&deg[ei[E + e]], 1);
}

// ---------------- scan stage 1: per-block chunk sums + degree histogram ----------------
__global__ __launch_bounds__(256) void scan_sum_k(const int* __restrict__ deg,
    int* __restrict__ bsum, int* __restrict__ deghist, int n)
{
    __shared__ int lh[256];
    const int t = threadIdx.x;
    lh[t] = 0;
    __syncthreads();
    const int i = blockIdx.x * SCAN_CHUNK + t;
    int s = 0;
    if (i < n) {
        s = deg[i];
        atomicAdd(&lh[min(s, 255)], 1);
    }
#pragma unroll
    for (int off = 32; off > 0; off >>= 1) s += __shfl_xor(s, off);
    __shared__ int ws_[4];
    const int lane = t & 63, w = t >> 6;
    if (lane == 0) ws_[w] = s;
    __syncthreads();
    if (t == 0) bsum[blockIdx.x] = ws_[0] + ws_[1] + ws_[2] + ws_[3];
    if (lh[t]) atomicAdd(&deghist[t], lh[t]);
}

// ---------------- scan stage 2: exclusive scans (block sums + degree bins) ----------------
__global__ __launch_bounds__(256) void scan_off_k(const int* __restrict__ bsum,
    int* __restrict__ boff, int* __restrict__ rowptr,
    const int* __restrict__ deghist, int* __restrict__ degcur, int nb, int n)
{
    const int t = threadIdx.x;
    const int lane = t & 63, w = t >> 6;
    int v = (t < nb) ? bsum[t] : 0;
    int inc = v;
#pragma unroll
    for (int off = 1; off < 64; off <<= 1) {
        int u = __shfl_up(inc, off);
        if (lane >= off) inc += u;
    }
    __shared__ int wsum[4], wpre[4];
    if (lane == 63) wsum[w] = inc;
    __syncthreads();
    if (t == 0) {
        int r = 0;
#pragma unroll
        for (int j = 0; j < 4; j++) { wpre[j] = r; r += wsum[j]; }
        rowptr[n] = r;
    }
    __syncthreads();
    if (t < nb) boff[t] = inc - v + wpre[w];
    int dv = deghist[t];
    int dinc = dv;
#pragma unroll
    for (int off = 1; off < 64; off <<= 1) {
        int u = __shfl_up(dinc, off);
        if (lane >= off) dinc += u;
    }
    __shared__ int w2sum[4], w2pre[4];
    if (lane == 63) w2sum[w] = dinc;
    __syncthreads();
    if (t == 0) {
        int r = 0;
#pragma unroll
        for (int j = 0; j < 4; j++) { w2pre[j] = r; r += w2sum[j]; }
    }
    __syncthreads();
    degcur[t] = dinc - dv + w2pre[w];
}

// ---------------- scan stage 3: rowptr + degree-sorted node order ----------------
__global__ __launch_bounds__(256) void scan_fin_k(int* __restrict__ deg,
    const int* __restrict__ boff, int* __restrict__ rowptr,
    int* __restrict__ degcur, int* __restrict__ nodeord, int n)
{
    __shared__ int wsum[4], wpre[4];
    __shared__ int lh[256], lbase[256];
    const int t = threadIdx.x;
    const int i = blockIdx.x * SCAN_CHUNK + t;
    lh[t] = 0;
    int v = (i < n) ? deg[i] : 0;
    const int bin = min(v, 255);
    const int lane = t & 63, w = t >> 6;
    int inc = v;
#pragma unroll
    for (int off = 1; off < 64; off <<= 1) {
        int u = __shfl_up(inc, off);
        if (lane >= off) inc += u;
    }
    if (lane == 63) wsum[w] = inc;
    __syncthreads();
    if (t == 0) {
        int r = 0;
#pragma unroll
        for (int j = 0; j < 4; j++) { wpre[j] = r; r += wsum[j]; }
    }
    __syncthreads();
    int rank = 0;
    if (i < n) {
        rank = atomicAdd(&lh[bin], 1);
        int ex = inc - v + wpre[w] + boff[blockIdx.x];
        rowptr[i] = ex;
        deg[i] = ex;                 // scatter cursor
    }
    __syncthreads();
    lbase[t] = lh[t] ? atomicAdd(&degcur[t], lh[t]) : 0;
    __syncthreads();
    if (i < n) nodeord[lbase[bin] + rank] = i;
}

// ---------------- CSR scatter: packed {src:16 | bf16(ea):16}; 1 edge/thread ----------------
__global__ __launch_bounds__(256) void scatter_k(const int* __restrict__ ei,
    const float* __restrict__ ea, int* __restrict__ cursor,
    unsigned* __restrict__ edges, int E)
{
    const int e = blockIdx.x * 256 + threadIdx.x;
    if (e >= E) return;
    const int dst = ei[E + e];
    const int pos = atomicAdd(&cursor[dst], 1);
    edges[pos] = ((unsigned)ei[e] << 16) | (unsigned)f2bf(ea[e]);
}

// ---------------- fused: edge logits + online softmax + aggregate
//                   + residual + GELU(erf) + BN-stats ----------------
// one 16-lane group per dst node (4 nodes/wave), descending-degree order;
// 2 edges/iter (independent chains), 2-ahead prefetch; shuffle-merged stats,
// coalesced partials write.
__global__ __launch_bounds__(256) void agg_k(const unsigned* __restrict__ xlb,
    const float* __restrict__ xr, const float* __restrict__ x,
    const float* __restrict__ bias, const int* __restrict__ rowptr,
    const unsigned* __restrict__ edges, const float* __restrict__ We,
    const float* __restrict__ att, const int* __restrict__ nodeord,
    unsigned* __restrict__ hbf, float* __restrict__ partials, int n)
{
    const int t = threadIdx.x;
    const int gg = (blockIdx.x * 256 + t) >> 4;
    const int li = t & 15;
    const int f0 = li * 8;
    const bool active = gg < n;

    float sum[8], sq[8];
#pragma unroll
    for (int k = 0; k < 8; k++) { sum[k] = 0.f; sq[k] = 0.f; }

    if (active) {
        const int v = nodeord[n - 1 - gg];   // descending degree
        const int beg = rowptr[v];
        const int end = rowptr[v + 1];

        float xrv[8], wev[8], atv[8];
        {
            float4 a0 = *(const float4*)(xr + (size_t)v * D + f0);
            float4 a1 = *(const float4*)(xr + (size_t)v * D + f0 + 4);
            xrv[0]=a0.x; xrv[1]=a0.y; xrv[2]=a0.z; xrv[3]=a0.w;
            xrv[4]=a1.x; xrv[5]=a1.y; xrv[6]=a1.z; xrv[7]=a1.w;
            float4 w0 = *(const float4*)(We + f0);
            float4 w1 = *(const float4*)(We + f0 + 4);
            wev[0]=w0.x; wev[1]=w0.y; wev[2]=w0.z; wev[3]=w0.w;
            wev[4]=w1.x; wev[5]=w1.y; wev[6]=w1.z; wev[7]=w1.w;
            float4 t0 = *(const float4*)(att + f0);
            float4 t1 = *(const float4*)(att + f0 + 4);
            atv[0]=t0.x; atv[1]=t0.y; atv[2]=t0.z; atv[3]=t0.w;
            atv[4]=t1.x; atv[5]=t1.y; atv[6]=t1.z; atv[7]=t1.w;
        }

        float m = -1e30f, s = 0.f;
        float acc[8];
#pragma unroll
        for (int k = 0; k < 8; k++) acc[k] = 0.f;

        int j = beg;
        unsigned pk0 = 0u, pk1 = 0u;
        uint4 xb0 = make_uint4(0,0,0,0), xb1 = make_uint4(0,0,0,0);
        if (j < end) {
            pk0 = edges[j];
            const int j1 = (j + 1 < end) ? j + 1 : end - 1;
            pk1 = edges[j1];
            xb0 = *(const uint4*)(xlb + (size_t)(pk0 >> 16) * 64 + li * 4);
            xb1 = *(const uint4*)(xlb + (size_t)(pk1 >> 16) * 64 + li * 4);
        }
        while (j < end) {
            const int jn = j + 2;
            unsigned pn0 = pk0, pn1 = pk1;
            uint4 xn0 = xb0, xn1 = xb1;
            if (jn < end) {
                pn0 = edges[jn];
                const int j3 = (jn + 1 < end) ? jn + 1 : end - 1;
                pn1 = edges[j3];
                xn0 = *(const uint4*)(xlb + (size_t)(pn0 >> 16) * 64 + li * 4);
                xn1 = *(const uint4*)(xlb + (size_t)(pn1 >> 16) * 64 + li * 4);
            }

            const float ea0 = bflo(pk0);
            const float ea1 = bflo(pk1);
            float xv0[8], xv1[8];
            xv0[0] = bflo(xb0.x); xv0[1] = bfhi(xb0.x);
            xv0[2] = bflo(xb0.y); xv0[3] = bfhi(xb0.y);
            xv0[4] = bflo(xb0.z); xv0[5] = bfhi(xb0.z);
            xv0[6] = bflo(xb0.w); xv0[7] = bfhi(xb0.w);
            xv1[0] = bflo(xb1.x); xv1[1] = bfhi(xb1.x);
            xv1[2] = bflo(xb1.y); xv1[3] = bfhi(xb1.y);
            xv1[4] = bflo(xb1.z); xv1[5] = bfhi(xb1.z);
            xv1[6] = bflo(xb1.w); xv1[7] = bfhi(xb1.w);

            float p0 = 0.f, p1 = 0.f;
#pragma unroll
            for (int k = 0; k < 8; k++) {
                float t0 = fmaf(ea0, wev[k], xrv[k]) + xv0[k];
                t0 = fmaxf(t0, 0.2f * t0);
                p0 = fmaf(t0, atv[k], p0);
                float t1 = fmaf(ea1, wev[k], xrv[k]) + xv1[k];
                t1 = fmaxf(t1, 0.2f * t1);
                p1 = fmaf(t1, atv[k], p1);
            }
#pragma unroll
            for (int off = 8; off >= 1; off >>= 1) {
                p0 += __shfl_xor(p0, off);
                p1 += __shfl_xor(p1, off);
            }
            if (j + 1 >= end) p1 = -1e30f;    // mask odd tail

            const float pm = fmaxf(m, fmaxf(p0, p1));
            const float sc = __expf(m - pm);
            const float w0 = __expf(p0 - pm);
            const float w1 = __expf(p1 - pm);
            s = s * sc + w0 + w1;
#pragma unroll
            for (int k = 0; k < 8; k++)
                acc[k] = fmaf(acc[k], sc, fmaf(w0, xv0[k], w1 * xv1[k]));
            m = pm;

            pk0 = pn0; pk1 = pn1; xb0 = xn0; xb1 = xn1; j = jn;
        }

        const float inv = 1.f / (s + 1e-16f);   // deg==0 -> acc=0
        float xa[8], bb[8];
        {
            float4 a0 = *(const float4*)(x + (size_t)v * D + f0);
            float4 a1 = *(const float4*)(x + (size_t)v * D + f0 + 4);
            xa[0]=a0.x; xa[1]=a0.y; xa[2]=a0.z; xa[3]=a0.w;
            xa[4]=a1.x; xa[5]=a1.y; xa[6]=a1.z; xa[7]=a1.w;
            float4 b0 = *(const float4*)(bias + f0);
            float4 b1 = *(const float4*)(bias + f0 + 4);
            bb[0]=b0.x; bb[1]=b0.y; bb[2]=b0.z; bb[3]=b0.w;
            bb[4]=b1.x; bb[5]=b1.y; bb[6]=b1.z; bb[7]=b1.w;
        }
        float ge[8];
#pragma unroll
        for (int k = 0; k < 8; k++) {
            const float hv = xa[k] + fmaf(acc[k], inv, bb[k]);
            const float g = 0.5f * hv * (1.f + erff(hv * 0.70710678118654752f));
            ge[k] = g;
            sum[k] = g;
            sq[k] = g * g;
        }
        unsigned o0 = (unsigned)f2bf(ge[0]) | ((unsigned)f2bf(ge[1]) << 16);
        unsigned o1 = (unsigned)f2bf(ge[2]) | ((unsigned)f2bf(ge[3]) << 16);
        unsigned o2 = (unsigned)f2bf(ge[4]) | ((unsigned)f2bf(ge[5]) << 16);
        unsigned o3 = (unsigned)f2bf(ge[6]) | ((unsigned)f2bf(ge[7]) << 16);
        *(uint4*)(hbf + (size_t)v * 64 + li * 4) = make_uint4(o0, o1, o2, o3);
    }

    // merge 4 groups of the wave via shuffles (lanes l, l^16, l^32 share f0)
#pragma unroll
    for (int k = 0; k < 8; k++) {
        sum[k] += __shfl_xor(sum[k], 16);
        sum[k] += __shfl_xor(sum[k], 32);
        sq[k]  += __shfl_xor(sq[k], 16);
        sq[k]  += __shfl_xor(sq[k], 32);
    }
    __shared__ float redS[4][128], redQ[4][128];
    const int wv_ = t >> 6;
    const int lane_ = t & 63;
    if (lane_ < 16) {
#pragma unroll
        for (int k = 0; k < 8; k++) {
            redS[wv_][f0 + k] = sum[k];
            redQ[wv_][f0 + k] = sq[k];
        }
    }
    __syncthreads();
    if (t < 128) {
        const float ts = redS[0][t] + redS[1][t] + redS[2][t] + redS[3][t];
        const float tq = redQ[0][t] + redQ[1][t] + redQ[2][t] + redQ[3][t];
        partials[(size_t)blockIdx.x * 256 + t] = ts;
        partials[(size_t)blockIdx.x * 256 + 128 + t] = tq;
    }
}

// ---------------- reduce partials + fold BN params ----------------
__global__ __launch_bounds__(256) void bn_reduce_params_k(const float* __restrict__ partials,
    const float* __restrict__ gamma, const float* __restrict__ beta,
    float* __restrict__ ab, float n, int nblk)
{
    const int c = blockIdx.x;      // 0..127
    const int t = threadIdx.x;     // 256
    float s = 0.f, q = 0.f;
    for (int b = t; b < nblk; b += 256) {
        s += partials[(size_t)b * 256 + c];
        q += partials[(size_t)b * 256 + 128 + c];
    }
#pragma unroll
    for (int off = 32; off > 0; off >>= 1) {
        s += __shfl_xor(s, off);
        q += __shfl_xor(q, off);
    }
    __shared__ float ss[4], qq[4];
    const int lane = t & 63, w = t >> 6;
    if (lane == 0) { ss[w] = s; qq[w] = q; }
    __syncthreads();
    if (t == 0) {
        float S = ss[0] + ss[1] + ss[2] + ss[3];
        float Q = qq[0] + qq[1] + qq[2] + qq[3];
        float mean = S / n;
        float var = Q / n - mean * mean;
        float a = rsqrtf(var + 1e-5f) * gamma[c];
        ab[c] = a;
        ab[c + 128] = beta[c] - mean * a;
    }
}

// ---------------- BN apply (bf16 h -> f32 out) ----------------
__global__ __launch_bounds__(256) void bn_apply_k(const unsigned* __restrict__ hbf,
    float* __restrict__ out, const float* __restrict__ ab, int total4)
{
    int i4 = blockIdx.x * blockDim.x + threadIdx.x;
    if (i4 >= total4) return;
    int cg = i4 & 31;
    uint2 hp = *(const uint2*)(hbf + (size_t)i4 * 2);
    float4 a = ((const float4*)ab)[cg];
    float4 b = ((const float4*)(ab + 128))[cg];
    ((float4*)out)[i4] = make_float4(bflo(hp.x) * a.x + b.x, bfhi(hp.x) * a.y + b.y,
                                     bflo(hp.y) * a.z + b.z, bfhi(hp.y) * a.w + b.w);
}

extern "C" void kernel_launch(void* const* d_in, const int* in_sizes, int n_in,
                              void* d_out, int out_size, void* d_ws, size_t ws_size,
                              hipStream_t stream)
{
    const float* x    = (const float*)d_in[0];
    const int*   ei   = (const int*)d_in[1];
    const float* ea   = (const float*)d_in[2];
    const float* Wl   = (const float*)d_in[3];
    const float* bl   = (const float*)d_in[4];
    const float* Wr   = (const float*)d_in[5];
    const float* br   = (const float*)d_in[6];
    const float* We   = (const float*)d_in[7];
    const float* att  = (const float*)d_in[8];
    const float* bias = (const float*)d_in[9];
    const float* gamma= (const float*)d_in[10];
    const float* beta = (const float*)d_in[11];
    float* out = (float*)d_out;

    const int n = in_sizes[0] / D;
    const int E = in_sizes[1] / 2;
    const int nb = (n + SCAN_CHUNK - 1) / SCAN_CHUNK;
    const int ablk = (n * 16 + 255) / 256;              // agg blocks (3125 @ n=50k)

    char* ws = (char*)d_ws;
    unsigned short* wpack = (unsigned short*)ws;        // 64 KB
    unsigned* xlb = (unsigned*)(ws + 65536);            // n*64 u32 (bf16 xl)
    unsigned* hbf = xlb + (size_t)n * 64;               // n*64 u32 (bf16 h)
    float* xr = (float*)(hbf + (size_t)n * 64);         // n*D f32
    int* deg = (int*)(xr + (size_t)n * D);              // n (becomes cursor)
    int* rowptr = deg + n;                              // n+1
    int* deghist = rowptr + n + 1;                      // 256
    int* degcur = deghist + 256;                        // 256
    int* nodeord = degcur + 256;                        // n
    int* bsum = nodeord + n;                            // nb
    int* boff = bsum + nb;                              // nb
    unsigned* edges = (unsigned*)(boff + nb);           // E u32 (packed src|ea)
    float* partials = (float*)(edges + E);              // 256*ablk
    float* ab = partials + (size_t)256 * ablk;          // 256

    const int nzb = 98;
    init_pack_k<<<16 + nzb, 256, 0, stream>>>(Wl, Wr, wpack, deg, deghist, n, nzb);
    const int nrt = (n + 15) / 16;
    gemm_mfma_k<<<(nrt + 3) / 4, 256, 0, stream>>>(x, wpack, bl, br, xlb, xr, n);
    hist_k<<<(E + 255) / 256, 256, 0, stream>>>(ei, deg, E);
    scan_sum_k<<<nb, 256, 0, stream>>>(deg, bsum, deghist, n);
    scan_off_k<<<1, 256, 0, stream>>>(bsum, boff, rowptr, deghist, degcur, nb, n);
    scan_fin_k<<<nb, 256, 0, stream>>>(deg, boff, rowptr, degcur, nodeord, n);
    scatter_k<<<(E + 255) / 256, 256, 0, stream>>>(ei, ea, deg, edges, E);
    agg_k<<<ablk, 256, 0, stream>>>(xlb, xr, x, bias, rowptr, edges, We, att,
                                    nodeord, hbf, partials, n);
    bn_reduce_params_k<<<128, 256, 0, stream>>>(partials, gamma, beta, ab, (float)n, ablk);
    const int total4 = (n * D) / 4;
    bn_apply_k<<<(total4 + 255) / 256, 256, 0, stream>>>(hbf, out, ab, total4);
}